// Round 1
// baseline (764.106 us; speedup 1.0000x reference)
//
#include <hip/hip_runtime.h>
#include <math.h>

#define NB 32
#define NN 1024
#define ND 1024
#define NO 1024
#define NH 512
#define NR 64

// ---------------- workspace offsets (in floats) ----------------
#define OFF_PART   0u         /* 131072  colsum partials (32*4*1024) */
#define OFF_PM     131072u    /* 32768 */
#define OFF_PMSQ   163840u    /* 32 */
#define OFF_ROWSQ  163872u    /* 32768 */
#define OFF_G      196640u    /* 32768 */
#define OFF_H0     229408u    /* 32768 */
#define OFF_H1     262176u    /* 16384 */
#define OFF_LOCAL  278560u    /* 16384 */
#define OFF_P1     294944u    /* 131072  w1 partials (8*32*512) */
#define OFF_P2     426016u    /* 65536   w2 partials (4*32*512) */
#define OFF_PG     491552u    /* 524288  wg partials (4*32*4096) */
#define OFF_PL     1015840u   /* 524288 */
#define OFF_AG     1540128u   /* 131072 */
#define OFF_AL     1671200u   /* 131072 */
#define OFF_MASK   1802272u   /* 2048 */
#define OFF_GAINS  1804320u   /* 2048 */
#define OFF_SCAL   1806368u   /* 128 */
#define OFF_MFIN   1806496u   /* 131072 */
#define OFF_C      1937568u   /* 2097152 */
#define OFF_PROJ   4034720u   /* 2097152 */
/* total 6131872 floats ~= 24.5 MB */

// ---------------- K0: column sums of pt = x[:,1:,:] ----------------
__global__ __launch_bounds__(256) void k0_colsum(const float* __restrict__ x, float* __restrict__ part){
  int tid = threadIdx.x;
  int nseg = blockIdx.x, dchunk = blockIdx.y, b = blockIdx.z;
  int d = dchunk*256 + tid;
  const float* xp = x + (size_t)b*NN*ND + d;
  int n0 = nseg*256;
  int nstart = (nseg==0) ? 1 : n0;
  float s = 0.f;
  #pragma unroll 8
  for(int n=nstart; n<n0+256; n++) s += xp[(size_t)n*ND];
  part[(size_t)(b*4+nseg)*1024 + d] = s;
}

// ---------------- K1: pm = colsum/1023, pmsq[b] = sum(pm^2)/D ----------------
__global__ __launch_bounds__(256) void k1_pmreduce(const float* __restrict__ part, float* __restrict__ pm, float* __restrict__ pmsq){
  __shared__ float red[256];
  int b = blockIdx.x, tid = threadIdx.x;
  float acc = 0.f;
  #pragma unroll
  for(int i=0;i<4;i++){
    int d = i*256 + tid;
    float s = part[(size_t)(b*4+0)*1024+d] + part[(size_t)(b*4+1)*1024+d]
            + part[(size_t)(b*4+2)*1024+d] + part[(size_t)(b*4+3)*1024+d];
    float p = s * (1.0f/1023.0f);
    pm[b*1024+d] = p;
    acc += p*p;
  }
  red[tid] = acc; __syncthreads();
  for(int o=128;o>0;o>>=1){ if(tid<o) red[tid]+=red[tid+o]; __syncthreads(); }
  if(tid==0) pmsq[b] = red[0]*(1.0f/1024.0f);
}

// ---------------- K2: proj = x @ basis^T; also rowsq, G=x.pm ----------------
__global__ __launch_bounds__(256) void k2_proj(const float* __restrict__ x, const float* __restrict__ basis,
    const float* __restrict__ pm, float* __restrict__ proj, float* __restrict__ rowsq, float* __restrict__ G){
  __shared__ __align__(16) float xs[64][68];
  __shared__ __align__(16) float bs[64][68];
  int tid = threadIdx.x;
  int row0 = blockIdx.x*64;
  int b = row0 >> 10;
  int lrow = tid>>4, lkv = tid&15;
  int rg = tid>>4, cg = tid&15;
  float acc[4][4];
  #pragma unroll
  for(int i_=0;i_<4;i_++){ acc[i_][0]=0.f; acc[i_][1]=0.f; acc[i_][2]=0.f; acc[i_][3]=0.f; }
  float sq[4]={0.f,0.f,0.f,0.f}, gp[4]={0.f,0.f,0.f,0.f};
  for(int kc=0;kc<16;kc++){
    int k0 = kc*64;
    float4 p4 = *(const float4*)&pm[(size_t)b*ND + k0 + lkv*4];
    #pragma unroll
    for(int i=0;i<4;i++){
      int r = lrow + 16*i;
      float4 v = *(const float4*)&x[((size_t)(row0+r))*ND + k0 + lkv*4];
      xs[lkv*4+0][r]=v.x; xs[lkv*4+1][r]=v.y; xs[lkv*4+2][r]=v.z; xs[lkv*4+3][r]=v.w;
      sq[i] += v.x*v.x + v.y*v.y + v.z*v.z + v.w*v.w;
      gp[i] += v.x*p4.x + v.y*p4.y + v.z*p4.z + v.w*p4.w;
      float4 u = *(const float4*)&basis[((size_t)r)*ND + k0 + lkv*4];
      bs[lkv*4+0][r]=u.x; bs[lkv*4+1][r]=u.y; bs[lkv*4+2][r]=u.z; bs[lkv*4+3][r]=u.w;
    }
    __syncthreads();
    #pragma unroll 8
    for(int kk=0;kk<64;kk++){
      float4 a = *(const float4*)&xs[kk][rg*4];
      float4 bb= *(const float4*)&bs[kk][cg*4];
      float ar[4]={a.x,a.y,a.z,a.w};
      float br[4]={bb.x,bb.y,bb.z,bb.w};
      #pragma unroll
      for(int i_=0;i_<4;i_++){
        #pragma unroll
        for(int j_=0;j_<4;j_++) acc[i_][j_] += ar[i_]*br[j_];
      }
    }
    __syncthreads();
  }
  #pragma unroll
  for(int i_=0;i_<4;i_++){
    float4 v = make_float4(acc[i_][0],acc[i_][1],acc[i_][2],acc[i_][3]);
    *(float4*)&proj[((size_t)(row0 + rg*4 + i_))*NR + cg*4] = v;
  }
  __syncthreads();
  #pragma unroll
  for(int i=0;i<4;i++){ int r = lrow+16*i; xs[r][lkv]=sq[i]; bs[r][lkv]=gp[i]; }
  __syncthreads();
  if(tid<64){
    float s=0.f, g=0.f;
    #pragma unroll
    for(int c=0;c<16;c++){ s+=xs[tid][c]; g+=bs[tid][c]; }
    rowsq[row0+tid]=s; G[row0+tid]=g;
  }
}

// ---------------- K3: scores, top-4, detail, LayerNorm -> h0 ----------------
__global__ __launch_bounds__(256) void k3_detail(const float* __restrict__ x, const float* __restrict__ rowsq,
    const float* __restrict__ G, const float* __restrict__ pmsq,
    const float* __restrict__ gamma_, const float* __restrict__ beta_, float* __restrict__ h0){
  __shared__ float sc[1024];
  __shared__ float rv[256];
  __shared__ int ri[256];
  __shared__ int topi[4];
  __shared__ float mred[256];
  int b = blockIdx.x, tid = threadIdx.x;
  float ps = pmsq[b];
  const float invD = 1.0f/1024.0f;
  for(int n=tid;n<1024;n+=256)
    sc[n] = (n==0) ? -INFINITY : (rowsq[b*1024+n] - 2.0f*G[b*1024+n])*invD + ps;
  __syncthreads();
  for(int t=0;t<4;t++){
    float bv = -INFINITY; int bi = 0x7fffffff;
    for(int n=tid;n<1024;n+=256){
      float v = sc[n];
      if(v>bv || (v==bv && n<bi)){ bv=v; bi=n; }
    }
    rv[tid]=bv; ri[tid]=bi;
    __syncthreads();
    for(int o=128;o>0;o>>=1){
      if(tid<o){
        float v=rv[tid+o]; int ii=ri[tid+o];
        if(v>rv[tid] || (v==rv[tid] && ii<ri[tid])){ rv[tid]=v; ri[tid]=ii; }
      }
      __syncthreads();
    }
    if(tid==0){ topi[t]=ri[0]; sc[ri[0]] = -INFINITY; }
    __syncthreads();
  }
  int i0=topi[0], i1=topi[1], i2=topi[2], i3=topi[3];
  float dv[4]; float dsum=0.f;
  #pragma unroll
  for(int jj=0;jj<4;jj++){
    int d = tid + jj*256;
    float v = 0.25f*(x[((size_t)(b*NN+i0))*ND+d] + x[((size_t)(b*NN+i1))*ND+d]
                   + x[((size_t)(b*NN+i2))*ND+d] + x[((size_t)(b*NN+i3))*ND+d]);
    dv[jj]=v; dsum+=v;
  }
  mred[tid]=dsum; __syncthreads();
  for(int o=128;o>0;o>>=1){ if(tid<o) mred[tid]+=mred[tid+o]; __syncthreads(); }
  float mu = mred[0]*invD;
  __syncthreads();
  float vs=0.f;
  #pragma unroll
  for(int jj=0;jj<4;jj++){ float t2=dv[jj]-mu; vs+=t2*t2; }
  mred[tid]=vs; __syncthreads();
  for(int o=128;o>0;o>>=1){ if(tid<o) mred[tid]+=mred[tid+o]; __syncthreads(); }
  float var = mred[0]*invD;
  float rstd = rsqrtf(var + 1e-5f);
  #pragma unroll
  for(int jj=0;jj<4;jj++){
    int d = tid + jj*256;
    h0[b*1024+d] = (dv[jj]-mu)*rstd*gamma_[d] + beta_[d];
  }
}

// ---------------- generic small GEMM (32 x Kd) @ (Kd x Ncols), k-split partials ----------------
// part[(ks*32 + r)*Ncols + col] = sum_{k in seg128} V[r*Kd+k] * W[k*Ncols+col]
__global__ __launch_bounds__(256) void gemm32_partial(const float* __restrict__ V, const float* __restrict__ W,
      float* __restrict__ part, int Kd, int Ncols){
  __shared__ __align__(16) float Vs[128][36];
  int col = blockIdx.x*256 + threadIdx.x;
  int k0 = blockIdx.y*128;
  for(int i=threadIdx.x; i<4096; i+=256){ int r=i>>7, k=i&127; Vs[k][r] = V[(size_t)r*Kd + k0 + k]; }
  __syncthreads();
  float acc[32];
  #pragma unroll
  for(int r=0;r<32;r++) acc[r]=0.f;
  for(int k=0;k<128;k++){
    float wv = W[(size_t)(k0+k)*Ncols + col];
    #pragma unroll
    for(int r4=0;r4<8;r4++){
      float4 v = *(const float4*)&Vs[k][r4*4];
      acc[r4*4+0]+=v.x*wv; acc[r4*4+1]+=v.y*wv; acc[r4*4+2]+=v.z*wv; acc[r4*4+3]+=v.w*wv;
    }
  }
  #pragma unroll
  for(int r=0;r<32;r++) part[((size_t)(blockIdx.y*32 + r))*Ncols + col] = acc[r];
}

// ---------------- reductions of partials ----------------
__global__ __launch_bounds__(256) void k_red_gelu(const float* __restrict__ part, const float* __restrict__ b1, float* __restrict__ h1){
  int id = blockIdx.x*256 + threadIdx.x;  // 16384
  int b_ = id >> 9, j = id & 511;
  float s = b1[j];
  #pragma unroll
  for(int ks=0;ks<8;ks++) s += part[(size_t)(ks*32+b_)*512 + j];
  h1[id] = 0.5f*s*(1.0f + erff(s*0.70710678118654752440f));
}
__global__ __launch_bounds__(256) void k_red_local(const float* __restrict__ part, const float* __restrict__ b2, float* __restrict__ lcl){
  int id = blockIdx.x*256 + threadIdx.x;  // 16384
  int b_ = id >> 9, j = id & 511;
  float s = b2[j];
  #pragma unroll
  for(int ks=0;ks<4;ks++) s += part[(size_t)(ks*32+b_)*512 + j];
  lcl[id] = s;
}
__global__ __launch_bounds__(256) void k_red_gl(const float* __restrict__ pg, const float* __restrict__ pl,
    const float* __restrict__ bg, const float* __restrict__ bl, float* __restrict__ Ag, float* __restrict__ Al){
  int id = blockIdx.x*256 + threadIdx.x;  // 131072
  int c = id & 4095;
  float sg = bg[c], sl = bl[c];
  #pragma unroll
  for(int ks=0;ks<4;ks++){
    sg += pg[(size_t)(ks*32)*4096 + (id>>12)*4096*0 + (size_t)(ks*32 + (id>>12))*0 ]; // placeholder (rewritten below)
    break;
  }
  // recompute cleanly:
  int b_ = id >> 12;
  sg = bg[c]; sl = bl[c];
  #pragma unroll
  for(int ks=0;ks<4;ks++){
    sg += pg[(size_t)(ks*32 + b_)*4096 + c];
    sl += pl[(size_t)(ks*32 + b_)*4096 + c];
  }
  Ag[id] = sg; Al[id] = sl;
}

// ---------------- heads: mode_mask, gains, alpha/beta/gate ----------------
__global__ __launch_bounds__(256) void k_heads(const float* __restrict__ context, const float* __restrict__ lcl,
    const float* __restrict__ wm, const float* __restrict__ bm,
    const float* __restrict__ wgain, const float* __restrict__ bgain,
    const float* __restrict__ wgate, const float* __restrict__ bgate,
    const float* __restrict__ wa, const float* __restrict__ ba,
    const float* __restrict__ wb, const float* __restrict__ bb,
    float* __restrict__ mask, float* __restrict__ gains, float* __restrict__ scal){
  __shared__ float fs[1024];
  __shared__ float redm[4][64];
  __shared__ float redg[4][64];
  __shared__ float ra[256], rb[256], rc[256];
  int b = blockIdx.x, tid = threadIdx.x;
  for(int i=tid;i<512;i+=256){ fs[i]=context[b*512+i]; fs[512+i]=lcl[b*512+i]; }
  __syncthreads();
  int j = tid & 63, kq = tid >> 6;
  float am=0.f, ag=0.f;
  for(int k=kq*256; k<kq*256+256; k++){ float f=fs[k]; am += f*wm[k*64+j]; ag += f*wgain[k*64+j]; }
  redm[kq][j]=am; redg[kq][j]=ag;
  float pa=0.f,pb=0.f,pg=0.f;
  #pragma unroll
  for(int i=0;i<4;i++){ int k=tid+256*i; float f=fs[k]; pa+=f*wa[k]; pb+=f*wb[k]; pg+=f*wgate[k]; }
  ra[tid]=pa; rb[tid]=pb; rc[tid]=pg;
  __syncthreads();
  if(tid<64){
    float m = redm[0][tid]+redm[1][tid]+redm[2][tid]+redm[3][tid] + bm[tid];
    mask[b*64+tid] = 1.0f/(1.0f+expf(-m));
    float g = redg[0][tid]+redg[1][tid]+redg[2][tid]+redg[3][tid] + bgain[tid];
    gains[b*64+tid] = 1.0f + 0.1f*tanhf(g);
  }
  for(int o=128;o>0;o>>=1){
    if(tid<o){ ra[tid]+=ra[tid+o]; rb[tid]+=rb[tid+o]; rc[tid]+=rc[tid+o]; }
    __syncthreads();
  }
  if(tid==0){
    scal[b*4+0] = 0.5f/(1.0f+expf(-(ra[0]+ba[0])));    // alpha
    scal[b*4+1] = 0.25f*tanhf(rb[0]+bb[0]);            // beta
    scal[b*4+2] = 1.0f/(1.0f+expf(-(rc[0]+bgate[0]))); // gate
  }
}

// ---------------- K7: mg/ml, comm, omega, expm (scaling+squaring Taylor), Mfin ----------------
__global__ __launch_bounds__(1024) void k7_expm(const float* __restrict__ Ag, const float* __restrict__ Al,
    const float* __restrict__ mask, const float* __restrict__ gains, const float* __restrict__ scal,
    float* __restrict__ Mfin){
  __shared__ __align__(16) float B0s[64][66];
  __shared__ __align__(16) float B1s[64][66];
  __shared__ __align__(16) float B2s[64][66];
  __shared__ float msks[64];
  __shared__ float colsum[64];
  __shared__ int ssh;
  int b = blockIdx.x, tid = threadIdx.x;
  int ig = tid>>5, jg = tid&31;
  int i0 = ig*2, j0 = jg*2;
  if(tid<64) msks[tid] = mask[b*64+tid];
  __syncthreads();
  float alpha = scal[b*4+0], bta = scal[b*4+1], gate = scal[b*4+2];
  const float* ag = Ag + b*4096;
  const float* al = Al + b*4096;
  #pragma unroll
  for(int di=0;di<2;di++){
    #pragma unroll
    for(int dj=0;dj<2;dj++){
      int i=i0+di, jx=j0+dj;
      float mm_ = msks[i]*msks[jx]*0.5f;
      B0s[i][jx] = mm_*(ag[i*64+jx]-ag[jx*64+i]);   // mg
      B1s[i][jx] = mm_*(al[i*64+jx]-al[jx*64+i]);   // ml
    }
  }
  __syncthreads();
  // B2 = ml@mg - mg@ml
  {
    float c00=0.f,c01=0.f,c10=0.f,c11=0.f;
    #pragma unroll 4
    for(int k=0;k<64;k++){
      float a0=B1s[i0][k], a1=B1s[i0+1][k];
      float m0=B0s[i0][k], m1=B0s[i0+1][k];
      float2 u = *(const float2*)&B0s[k][j0];
      float2 w = *(const float2*)&B1s[k][j0];
      c00 += a0*u.x - m0*w.x;  c01 += a0*u.y - m0*w.y;
      c10 += a1*u.x - m1*w.x;  c11 += a1*u.y - m1*w.y;
    }
    B2s[i0][j0]=c00; B2s[i0][j0+1]=c01; B2s[i0+1][j0]=c10; B2s[i0+1][j0+1]=c11;
  }
  __syncthreads();
  const float bc = bta*(1.0f/12.0f);
  #pragma unroll
  for(int di=0;di<2;di++){
    #pragma unroll
    for(int dj=0;dj<2;dj++){
      int i=i0+di, jx=j0+dj;
      B0s[i][jx] = alpha*0.5f*(B0s[i][jx]+B1s[i][jx]) + bc*B2s[i][jx];  // omega
    }
  }
  __syncthreads();
  if(tid<64){
    float s=0.f;
    for(int i=0;i<64;i++) s += fabsf(B0s[i][tid]);
    colsum[tid]=s;
  }
  __syncthreads();
  if(tid==0){
    float m=0.f;
    for(int jx=0;jx<64;jx++) m = fmaxf(m, colsum[jx]);
    int s=0;
    while(m>0.5f && s<30){ m*=0.5f; s++; }
    ssh = s;
  }
  __syncthreads();
  int sh = ssh;
  float scl = ldexpf(1.0f, -sh);
  #pragma unroll
  for(int di=0;di<2;di++){
    #pragma unroll
    for(int dj=0;dj<2;dj++){ int i=i0+di,jx=j0+dj; B0s[i][jx]*=scl; }
  }
  __syncthreads();
  // Horner: P = I + A/8
  #pragma unroll
  for(int di=0;di<2;di++){
    #pragma unroll
    for(int dj=0;dj<2;dj++){
      int i=i0+di, jx=j0+dj;
      B1s[i][jx] = ((i==jx)?1.0f:0.0f) + B0s[i][jx]*0.125f;
    }
  }
  __syncthreads();
  for(int kk=7;kk>=1;kk--){
    float c00=0.f,c01=0.f,c10=0.f,c11=0.f;
    #pragma unroll 4
    for(int k=0;k<64;k++){
      float a0=B0s[i0][k], a1=B0s[i0+1][k];
      float2 u = *(const float2*)&B1s[k][j0];
      c00+=a0*u.x; c01+=a0*u.y; c10+=a1*u.x; c11+=a1*u.y;
    }
    B2s[i0][j0]=c00; B2s[i0][j0+1]=c01; B2s[i0+1][j0]=c10; B2s[i0+1][j0+1]=c11;
    __syncthreads();
    float inv = 1.0f/(float)kk;
    #pragma unroll
    for(int di=0;di<2;di++){
      #pragma unroll
      for(int dj=0;dj<2;dj++){
        int i=i0+di, jx=j0+dj;
        B1s[i][jx] = ((i==jx)?1.0f:0.0f) + B2s[i][jx]*inv;
      }
    }
    __syncthreads();
  }
  float (*Q)[66] = B1s; float (*T)[66] = B2s;
  for(int t=0;t<sh;t++){
    float c00=0.f,c01=0.f,c10=0.f,c11=0.f;
    #pragma unroll 4
    for(int k=0;k<64;k++){
      float a0=Q[i0][k], a1=Q[i0+1][k];
      float2 u = *(const float2*)&Q[k][j0];
      c00+=a0*u.x; c01+=a0*u.y; c10+=a1*u.x; c11+=a1*u.y;
    }
    T[i0][j0]=c00; T[i0][j0+1]=c01; T[i0+1][j0]=c10; T[i0+1][j0+1]=c11;
    __syncthreads();
    float (*tmp)[66]=Q; Q=T; T=tmp;
  }
  float g0 = gains[b*64+j0], g1 = gains[b*64+j0+1];
  float* mf = Mfin + b*4096;
  #pragma unroll
  for(int di=0;di<2;di++){
    int i=i0+di;
    float2 v;
    v.x = gate*(Q[i][j0]*g0   - ((i==j0)?1.0f:0.0f));
    v.y = gate*(Q[i][j0+1]*g1 - ((i==j0+1)?1.0f:0.0f));
    *(float2*)&mf[i*64+j0] = v;
  }
}

// ---------------- K8: C_b = Mfin_b @ output_basis ----------------
__global__ __launch_bounds__(256) void k8_cmat(const float* __restrict__ Mfin, const float* __restrict__ ob, float* __restrict__ C){
  __shared__ __align__(16) float MT[64][68];
  int b = blockIdx.y; int o0 = blockIdx.x*128;
  int tid = threadIdx.x;
  for(int idx=tid; idx<4096; idx+=256){ int i=idx>>6, k=idx&63; MT[k][i] = Mfin[b*4096+idx]; }
  __syncthreads();
  int cg = tid&31, rg = tid>>5;
  float acc[8][4];
  #pragma unroll
  for(int r=0;r<8;r++){ acc[r][0]=0.f; acc[r][1]=0.f; acc[r][2]=0.f; acc[r][3]=0.f; }
  for(int k=0;k<64;k++){
    float4 bv = *(const float4*)&ob[(size_t)k*NO + o0 + cg*4];
    float4 a0 = *(const float4*)&MT[k][rg*8];
    float4 a1 = *(const float4*)&MT[k][rg*8+4];
    float arr[8]={a0.x,a0.y,a0.z,a0.w,a1.x,a1.y,a1.z,a1.w};
    #pragma unroll
    for(int r=0;r<8;r++){
      acc[r][0]+=arr[r]*bv.x; acc[r][1]+=arr[r]*bv.y; acc[r][2]+=arr[r]*bv.z; acc[r][3]+=arr[r]*bv.w;
    }
  }
  #pragma unroll
  for(int r=0;r<8;r++){
    *(float4*)&C[((size_t)(b*64 + rg*8+r))*NO + o0 + cg*4] = make_float4(acc[r][0],acc[r][1],acc[r][2],acc[r][3]);
  }
}

// ---------------- K9: out_b = proj_b @ C_b ----------------
__global__ __launch_bounds__(256) void k9_out(const float* __restrict__ proj, const float* __restrict__ C, float* __restrict__ out){
  __shared__ __align__(16) float PT[64][132];
  __shared__ __align__(16) float CS[64][68];
  int b = blockIdx.z; int row0 = blockIdx.y*128; int o0 = blockIdx.x*64;
  int tid = threadIdx.x;
  #pragma unroll
  for(int i=0;i<8;i++){
    int f = tid + 256*i; int r = f>>4; int kv = f&15;
    float4 v = *(const float4*)&proj[((size_t)(b*NN + row0 + r))*NR + kv*4];
    PT[kv*4+0][r]=v.x; PT[kv*4+1][r]=v.y; PT[kv*4+2][r]=v.z; PT[kv*4+3][r]=v.w;
  }
  #pragma unroll
  for(int i=0;i<4;i++){
    int f = tid + 256*i; int k = f>>4; int kv = f&15;
    *(float4*)&CS[k][kv*4] = *(const float4*)&C[((size_t)(b*NR + k))*NO + o0 + kv*4];
  }
  __syncthreads();
  int rg = tid>>4, cg = tid&15;
  float acc[8][4];
  #pragma unroll
  for(int r=0;r<8;r++){ acc[r][0]=0.f; acc[r][1]=0.f; acc[r][2]=0.f; acc[r][3]=0.f; }
  #pragma unroll 8
  for(int k=0;k<64;k++){
    float4 bv = *(const float4*)&CS[k][cg*4];
    float4 a0 = *(const float4*)&PT[k][rg*8];
    float4 a1 = *(const float4*)&PT[k][rg*8+4];
    float arr[8]={a0.x,a0.y,a0.z,a0.w,a1.x,a1.y,a1.z,a1.w};
    #pragma unroll
    for(int r=0;r<8;r++){
      acc[r][0]+=arr[r]*bv.x; acc[r][1]+=arr[r]*bv.y; acc[r][2]+=arr[r]*bv.z; acc[r][3]+=arr[r]*bv.w;
    }
  }
  #pragma unroll
  for(int r=0;r<8;r++){
    *(float4*)&out[((size_t)(b*NN + row0 + rg*8 + r))*NO + o0 + cg*4] =
        make_float4(acc[r][0],acc[r][1],acc[r][2],acc[r][3]);
  }
}

extern "C" void kernel_launch(void* const* d_in, const int* in_sizes, int n_in,
                              void* d_out, int out_size, void* d_ws, size_t ws_size,
                              hipStream_t stream) {
  (void)in_sizes; (void)n_in; (void)out_size; (void)ws_size;
  const float* x       = (const float*)d_in[0];
  const float* context = (const float*)d_in[1];
  const float* ibasis  = (const float*)d_in[2];
  const float* obasis  = (const float*)d_in[3];
  const float* lng     = (const float*)d_in[4];
  const float* lnb     = (const float*)d_in[5];
  const float* w1      = (const float*)d_in[6];
  const float* b1      = (const float*)d_in[7];
  const float* w2      = (const float*)d_in[8];
  const float* b2      = (const float*)d_in[9];
  const float* wg      = (const float*)d_in[10];
  const float* bg      = (const float*)d_in[11];
  const float* wl      = (const float*)d_in[12];
  const float* bl      = (const float*)d_in[13];
  const float* wm      = (const float*)d_in[14];
  const float* bm      = (const float*)d_in[15];
  const float* wgain   = (const float*)d_in[16];
  const float* bgain   = (const float*)d_in[17];
  const float* wgate   = (const float*)d_in[18];
  const float* bgate   = (const float*)d_in[19];
  const float* wa      = (const float*)d_in[20];
  const float* ba      = (const float*)d_in[21];
  const float* wb      = (const float*)d_in[22];
  const float* bb      = (const float*)d_in[23];
  float* out = (float*)d_out;
  float* ws  = (float*)d_ws;

  float* part  = ws + OFF_PART;
  float* pm    = ws + OFF_PM;
  float* pmsq  = ws + OFF_PMSQ;
  float* rowsq = ws + OFF_ROWSQ;
  float* G     = ws + OFF_G;
  float* h0    = ws + OFF_H0;
  float* h1    = ws + OFF_H1;
  float* lcl   = ws + OFF_LOCAL;
  float* p1    = ws + OFF_P1;
  float* p2    = ws + OFF_P2;
  float* pg_   = ws + OFF_PG;
  float* pl_   = ws + OFF_PL;
  float* Ag    = ws + OFF_AG;
  float* Al    = ws + OFF_AL;
  float* mask  = ws + OFF_MASK;
  float* gains = ws + OFF_GAINS;
  float* scal  = ws + OFF_SCAL;
  float* Mfin  = ws + OFF_MFIN;
  float* Cb    = ws + OFF_C;
  float* proj  = ws + OFF_PROJ;

  k0_colsum<<<dim3(4,4,NB),256,0,stream>>>(x, part);
  k1_pmreduce<<<NB,256,0,stream>>>(part, pm, pmsq);
  k2_proj<<<512,256,0,stream>>>(x, ibasis, pm, proj, rowsq, G);
  k3_detail<<<NB,256,0,stream>>>(x, rowsq, G, pmsq, lng, lnb, h0);
  gemm32_partial<<<dim3(2,8),256,0,stream>>>(h0, w1, p1, 1024, 512);
  k_red_gelu<<<64,256,0,stream>>>(p1, b1, h1);
  gemm32_partial<<<dim3(2,4),256,0,stream>>>(h1, w2, p2, 512, 512);
  k_red_local<<<64,256,0,stream>>>(p2, b2, lcl);
  gemm32_partial<<<dim3(16,4),256,0,stream>>>(context, wg, pg_, 512, 4096);
  gemm32_partial<<<dim3(16,4),256,0,stream>>>(lcl, wl, pl_, 512, 4096);
  k_red_gl<<<512,256,0,stream>>>(pg_, pl_, bg, bl, Ag, Al);
  k_heads<<<NB,256,0,stream>>>(context, lcl, wm, bm, wgain, bgain, wgate, bgate, wa, ba, wb, bb, mask, gains, scal);
  k7_expm<<<NB,1024,0,stream>>>(Ag, Al, mask, gains, scal, Mfin);
  k8_cmat<<<dim3(8,NB),256,0,stream>>>(Mfin, obasis, Cb);
  k9_out<<<dim3(16,8,NB),256,0,stream>>>(proj, Cb, out);
}

// Round 2
// 611.537 us; speedup vs baseline: 1.2495x; 1.2495x over previous
//
#include <hip/hip_runtime.h>
#include <math.h>

#define NB 32
#define NN 1024
#define ND 1024
#define NO 1024
#define NH 512
#define NR 64

// ---------------- workspace offsets (in floats) ----------------
// NOTE: colsum partials (32*16*1024 = 524288) alias OFF_PG: k0/k1 finish
// before the wg GEMM writes pg_ (stream-ordered), sizes match exactly.
#define OFF_PM     0u         /* 32768 */
#define OFF_PMSQ   32768u     /* 32 */
#define OFF_ROWSQ  32800u     /* 32768 */
#define OFF_G      65568u     /* 32768 */
#define OFF_H0     98336u     /* 32768 */
#define OFF_H1     131104u    /* 16384 */
#define OFF_LOCAL  147488u    /* 16384 */
#define OFF_P1     163872u    /* 131072  w1 partials (8*32*512) */
#define OFF_P2     294944u    /* 65536   w2 partials (4*32*512) */
#define OFF_PG     360480u    /* 524288  wg partials (4*32*4096)  == colsum part */
#define OFF_PL     884768u    /* 524288 */
#define OFF_AG     1409056u   /* 131072 */
#define OFF_AL     1540128u   /* 131072 */
#define OFF_MASK   1671200u   /* 2048 */
#define OFF_GAINS  1673248u   /* 2048 */
#define OFF_SCAL   1675296u   /* 128 */
#define OFF_MFIN   1675424u   /* 131072 */
#define OFF_C      1806496u   /* 2097152 */
#define OFF_PROJ   3903648u   /* 2097152 */
/* total 6000800 floats ~= 24.0 MB (<= proven 24.5 MB) */

// ---------------- K0: column sums of pt = x[:,1:,:]  (float4, 16 n-segments) ----------------
__global__ __launch_bounds__(256) void k0_colsum(const float* __restrict__ x, float* __restrict__ part){
  int tid = threadIdx.x;
  int nseg = blockIdx.x, b = blockIdx.y;
  int d4 = tid*4;
  const float* xp = x + (size_t)b*NN*ND + d4;
  int nstart = nseg*64; if(nseg==0) nstart = 1;
  int nend = nseg*64 + 64;
  float sx=0.f, sy=0.f, sz=0.f, sw=0.f;
  #pragma unroll 4
  for(int n=nstart; n<nend; n++){
    float4 v = *(const float4*)&xp[(size_t)n*ND];
    sx+=v.x; sy+=v.y; sz+=v.z; sw+=v.w;
  }
  *(float4*)&part[(size_t)(b*16+nseg)*1024 + d4] = make_float4(sx,sy,sz,sw);
}

// ---------------- K1: pm = colsum/1023, pmsq[b] = sum(pm^2)/D ----------------
__global__ __launch_bounds__(256) void k1_pmreduce(const float* __restrict__ part, float* __restrict__ pm, float* __restrict__ pmsq){
  __shared__ float red[256];
  int b = blockIdx.x, tid = threadIdx.x;
  float acc = 0.f;
  #pragma unroll
  for(int i=0;i<4;i++){
    int d = i*256 + tid;
    float s = 0.f;
    #pragma unroll
    for(int ks=0;ks<16;ks++) s += part[(size_t)(b*16+ks)*1024 + d];
    float p = s * (1.0f/1023.0f);
    pm[b*1024+d] = p;
    acc += p*p;
  }
  red[tid] = acc; __syncthreads();
  for(int o=128;o>0;o>>=1){ if(tid<o) red[tid]+=red[tid+o]; __syncthreads(); }
  if(tid==0) pmsq[b] = red[0]*(1.0f/1024.0f);
}

// ---------------- K2: proj = x @ basis^T; also rowsq, G=x.pm ----------------
__global__ __launch_bounds__(256) void k2_proj(const float* __restrict__ x, const float* __restrict__ basis,
    const float* __restrict__ pm, float* __restrict__ proj, float* __restrict__ rowsq, float* __restrict__ G){
  __shared__ __align__(16) float xs[64][68];
  __shared__ __align__(16) float bs[64][68];
  int tid = threadIdx.x;
  int row0 = blockIdx.x*64;
  int b = row0 >> 10;
  int lrow = tid>>4, lkv = tid&15;
  int rg = tid>>4, cg = tid&15;
  float acc[4][4];
  #pragma unroll
  for(int i_=0;i_<4;i_++){ acc[i_][0]=0.f; acc[i_][1]=0.f; acc[i_][2]=0.f; acc[i_][3]=0.f; }
  float sq[4]={0.f,0.f,0.f,0.f}, gp[4]={0.f,0.f,0.f,0.f};
  for(int kc=0;kc<16;kc++){
    int k0 = kc*64;
    float4 p4 = *(const float4*)&pm[(size_t)b*ND + k0 + lkv*4];
    #pragma unroll
    for(int i=0;i<4;i++){
      int r = lrow + 16*i;
      float4 v = *(const float4*)&x[((size_t)(row0+r))*ND + k0 + lkv*4];
      xs[lkv*4+0][r]=v.x; xs[lkv*4+1][r]=v.y; xs[lkv*4+2][r]=v.z; xs[lkv*4+3][r]=v.w;
      sq[i] += v.x*v.x + v.y*v.y + v.z*v.z + v.w*v.w;
      gp[i] += v.x*p4.x + v.y*p4.y + v.z*p4.z + v.w*p4.w;
      float4 u = *(const float4*)&basis[((size_t)r)*ND + k0 + lkv*4];
      bs[lkv*4+0][r]=u.x; bs[lkv*4+1][r]=u.y; bs[lkv*4+2][r]=u.z; bs[lkv*4+3][r]=u.w;
    }
    __syncthreads();
    #pragma unroll 8
    for(int kk=0;kk<64;kk++){
      float4 a = *(const float4*)&xs[kk][rg*4];
      float4 bb= *(const float4*)&bs[kk][cg*4];
      float ar[4]={a.x,a.y,a.z,a.w};
      float br[4]={bb.x,bb.y,bb.z,bb.w};
      #pragma unroll
      for(int i_=0;i_<4;i_++){
        #pragma unroll
        for(int j_=0;j_<4;j_++) acc[i_][j_] += ar[i_]*br[j_];
      }
    }
    __syncthreads();
  }
  #pragma unroll
  for(int i_=0;i_<4;i_++){
    float4 v = make_float4(acc[i_][0],acc[i_][1],acc[i_][2],acc[i_][3]);
    *(float4*)&proj[((size_t)(row0 + rg*4 + i_))*NR + cg*4] = v;
  }
  __syncthreads();
  #pragma unroll
  for(int i=0;i<4;i++){ int r = lrow+16*i; xs[r][lkv]=sq[i]; bs[r][lkv]=gp[i]; }
  __syncthreads();
  if(tid<64){
    float s=0.f, g=0.f;
    #pragma unroll
    for(int c=0;c<16;c++){ s+=xs[tid][c]; g+=bs[tid][c]; }
    rowsq[row0+tid]=s; G[row0+tid]=g;
  }
}

// ---------------- K3: scores, top-4, detail, LayerNorm -> h0 ----------------
__global__ __launch_bounds__(256) void k3_detail(const float* __restrict__ x, const float* __restrict__ rowsq,
    const float* __restrict__ G, const float* __restrict__ pmsq,
    const float* __restrict__ gamma_, const float* __restrict__ beta_, float* __restrict__ h0){
  __shared__ float sc[1024];
  __shared__ float rv[256];
  __shared__ int ri[256];
  __shared__ int topi[4];
  __shared__ float mred[256];
  int b = blockIdx.x, tid = threadIdx.x;
  float ps = pmsq[b];
  const float invD = 1.0f/1024.0f;
  for(int n=tid;n<1024;n+=256)
    sc[n] = (n==0) ? -INFINITY : (rowsq[b*1024+n] - 2.0f*G[b*1024+n])*invD + ps;
  __syncthreads();
  for(int t=0;t<4;t++){
    float bv = -INFINITY; int bi = 0x7fffffff;
    for(int n=tid;n<1024;n+=256){
      float v = sc[n];
      if(v>bv || (v==bv && n<bi)){ bv=v; bi=n; }
    }
    rv[tid]=bv; ri[tid]=bi;
    __syncthreads();
    for(int o=128;o>0;o>>=1){
      if(tid<o){
        float v=rv[tid+o]; int ii=ri[tid+o];
        if(v>rv[tid] || (v==rv[tid] && ii<ri[tid])){ rv[tid]=v; ri[tid]=ii; }
      }
      __syncthreads();
    }
    if(tid==0){ topi[t]=ri[0]; sc[ri[0]] = -INFINITY; }
    __syncthreads();
  }
  int i0=topi[0], i1=topi[1], i2=topi[2], i3=topi[3];
  float dv[4]; float dsum=0.f;
  #pragma unroll
  for(int jj=0;jj<4;jj++){
    int d = tid + jj*256;
    float v = 0.25f*(x[((size_t)(b*NN+i0))*ND+d] + x[((size_t)(b*NN+i1))*ND+d]
                   + x[((size_t)(b*NN+i2))*ND+d] + x[((size_t)(b*NN+i3))*ND+d]);
    dv[jj]=v; dsum+=v;
  }
  mred[tid]=dsum; __syncthreads();
  for(int o=128;o>0;o>>=1){ if(tid<o) mred[tid]+=mred[tid+o]; __syncthreads(); }
  float mu = mred[0]*invD;
  __syncthreads();
  float vs=0.f;
  #pragma unroll
  for(int jj=0;jj<4;jj++){ float t2=dv[jj]-mu; vs+=t2*t2; }
  mred[tid]=vs; __syncthreads();
  for(int o=128;o>0;o>>=1){ if(tid<o) mred[tid]+=mred[tid+o]; __syncthreads(); }
  float var = mred[0]*invD;
  float rstd = rsqrtf(var + 1e-5f);
  #pragma unroll
  for(int jj=0;jj<4;jj++){
    int d = tid + jj*256;
    h0[b*1024+d] = (dv[jj]-mu)*rstd*gamma_[d] + beta_[d];
  }
}

// ---------------- generic small GEMM (32 x Kd) @ (Kd x Ncols), k-split partials ----------------
__global__ __launch_bounds__(256) void gemm32_partial(const float* __restrict__ V, const float* __restrict__ W,
      float* __restrict__ part, int Kd, int Ncols){
  __shared__ __align__(16) float Vs[128][36];
  int col = blockIdx.x*256 + threadIdx.x;
  int k0 = blockIdx.y*128;
  for(int i=threadIdx.x; i<4096; i+=256){ int r=i>>7, k=i&127; Vs[k][r] = V[(size_t)r*Kd + k0 + k]; }
  __syncthreads();
  float acc[32];
  #pragma unroll
  for(int r=0;r<32;r++) acc[r]=0.f;
  #pragma unroll 4
  for(int k=0;k<128;k++){
    float wv = W[(size_t)(k0+k)*Ncols + col];
    #pragma unroll
    for(int r4=0;r4<8;r4++){
      float4 v = *(const float4*)&Vs[k][r4*4];
      acc[r4*4+0]+=v.x*wv; acc[r4*4+1]+=v.y*wv; acc[r4*4+2]+=v.z*wv; acc[r4*4+3]+=v.w*wv;
    }
  }
  #pragma unroll
  for(int r=0;r<32;r++) part[((size_t)(blockIdx.y*32 + r))*Ncols + col] = acc[r];
}

// ---------------- reductions of partials ----------------
__global__ __launch_bounds__(256) void k_red_gelu(const float* __restrict__ part, const float* __restrict__ b1, float* __restrict__ h1){
  int id = blockIdx.x*256 + threadIdx.x;  // 16384
  int b_ = id >> 9, j = id & 511;
  float s = b1[j];
  #pragma unroll
  for(int ks=0;ks<8;ks++) s += part[(size_t)(ks*32+b_)*512 + j];
  h1[id] = 0.5f*s*(1.0f + erff(s*0.70710678118654752440f));
}
__global__ __launch_bounds__(256) void k_red_local(const float* __restrict__ part, const float* __restrict__ b2, float* __restrict__ lcl){
  int id = blockIdx.x*256 + threadIdx.x;  // 16384
  int b_ = id >> 9, j = id & 511;
  float s = b2[j];
  #pragma unroll
  for(int ks=0;ks<4;ks++) s += part[(size_t)(ks*32+b_)*512 + j];
  lcl[id] = s;
}
__global__ __launch_bounds__(256) void k_red_gl(const float* __restrict__ pg, const float* __restrict__ pl,
    const float* __restrict__ bg, const float* __restrict__ bl, float* __restrict__ Ag, float* __restrict__ Al){
  int id = blockIdx.x*256 + threadIdx.x;  // 131072
  int c = id & 4095;
  int b_ = id >> 12;
  float sg = bg[c], sl = bl[c];
  #pragma unroll
  for(int ks=0;ks<4;ks++){
    sg += pg[(size_t)(ks*32 + b_)*4096 + c];
    sl += pl[(size_t)(ks*32 + b_)*4096 + c];
  }
  Ag[id] = sg; Al[id] = sl;
}

// ---------------- heads: mode_mask, gains, alpha/beta/gate ----------------
// 1024 threads: 16 waves each own a 64-row k-slice of wm/wgain (coalesced
// 256B row loads, unroll-8 => many loads in flight), LDS tree-reduce.
__global__ __launch_bounds__(1024) void k_heads(const float* __restrict__ context, const float* __restrict__ lcl,
    const float* __restrict__ wm, const float* __restrict__ bm,
    const float* __restrict__ wgain, const float* __restrict__ bgain,
    const float* __restrict__ wgate, const float* __restrict__ bgate,
    const float* __restrict__ wa, const float* __restrict__ ba,
    const float* __restrict__ wb, const float* __restrict__ bb,
    float* __restrict__ mask, float* __restrict__ gains, float* __restrict__ scal){
  __shared__ float fs[1024];
  __shared__ float redm[16][64];
  __shared__ float redg[16][64];
  __shared__ float wra[16], wrb[16], wrg[16];
  int b = blockIdx.x, tid = threadIdx.x;
  fs[tid] = (tid < 512) ? context[b*512 + tid] : lcl[b*512 + tid - 512];
  __syncthreads();
  int j = tid & 63, kq = tid >> 6;   // lane, wave
  const float* wmp = wm    + (size_t)(kq*64)*64 + j;
  const float* wgp = wgain + (size_t)(kq*64)*64 + j;
  float am = 0.f, ag = 0.f;
  #pragma unroll 8
  for(int k=0;k<64;k++){
    float f = fs[kq*64 + k];
    am += f * wmp[k*64];
    ag += f * wgp[k*64];
  }
  redm[kq][j] = am; redg[kq][j] = ag;
  // scalar head partials (wa, wb, wgate are 1024-vectors)
  float f = fs[tid];
  float pa = f*wa[tid], pb = f*wb[tid], pg = f*wgate[tid];
  #pragma unroll
  for(int o=32;o>0;o>>=1){
    pa += __shfl_down(pa, o);
    pb += __shfl_down(pb, o);
    pg += __shfl_down(pg, o);
  }
  if(j == 0){ wra[kq]=pa; wrb[kq]=pb; wrg[kq]=pg; }
  __syncthreads();
  for(int o=8;o>0;o>>=1){
    if(kq < o){ redm[kq][j] += redm[kq+o][j]; redg[kq][j] += redg[kq+o][j]; }
    __syncthreads();
  }
  if(tid < 64){
    float m = redm[0][tid] + bm[tid];
    mask[b*64+tid] = 1.0f/(1.0f+expf(-m));
    float g = redg[0][tid] + bgain[tid];
    gains[b*64+tid] = 1.0f + 0.1f*tanhf(g);
  }
  if(tid == 0){
    float sa=0.f, sb=0.f, sg=0.f;
    #pragma unroll
    for(int i=0;i<16;i++){ sa+=wra[i]; sb+=wrb[i]; sg+=wrg[i]; }
    scal[b*4+0] = 0.5f/(1.0f+expf(-(sa+ba[0])));    // alpha
    scal[b*4+1] = 0.25f*tanhf(sb+bb[0]);            // beta
    scal[b*4+2] = 1.0f/(1.0f+expf(-(sg+bgate[0]))); // gate
  }
}

// ---------------- K7: mg/ml, comm, omega, expm (scaling+squaring Taylor), Mfin ----------------
__global__ __launch_bounds__(1024) void k7_expm(const float* __restrict__ Ag, const float* __restrict__ Al,
    const float* __restrict__ mask, const float* __restrict__ gains, const float* __restrict__ scal,
    float* __restrict__ Mfin){
  __shared__ __align__(16) float B0s[64][66];
  __shared__ __align__(16) float B1s[64][66];
  __shared__ __align__(16) float B2s[64][66];
  __shared__ float msks[64];
  __shared__ float colsum[64];
  __shared__ int ssh;
  int b = blockIdx.x, tid = threadIdx.x;
  int ig = tid>>5, jg = tid&31;
  int i0 = ig*2, j0 = jg*2;
  if(tid<64) msks[tid] = mask[b*64+tid];
  __syncthreads();
  float alpha = scal[b*4+0], bta = scal[b*4+1], gate = scal[b*4+2];
  const float* ag = Ag + b*4096;
  const float* al = Al + b*4096;
  #pragma unroll
  for(int di=0;di<2;di++){
    #pragma unroll
    for(int dj=0;dj<2;dj++){
      int i=i0+di, jx=j0+dj;
      float mm_ = msks[i]*msks[jx]*0.5f;
      B0s[i][jx] = mm_*(ag[i*64+jx]-ag[jx*64+i]);   // mg
      B1s[i][jx] = mm_*(al[i*64+jx]-al[jx*64+i]);   // ml
    }
  }
  __syncthreads();
  // B2 = ml@mg - mg@ml
  {
    float c00=0.f,c01=0.f,c10=0.f,c11=0.f;
    #pragma unroll 4
    for(int k=0;k<64;k++){
      float a0=B1s[i0][k], a1=B1s[i0+1][k];
      float m0=B0s[i0][k], m1=B0s[i0+1][k];
      float2 u = *(const float2*)&B0s[k][j0];
      float2 w = *(const float2*)&B1s[k][j0];
      c00 += a0*u.x - m0*w.x;  c01 += a0*u.y - m0*w.y;
      c10 += a1*u.x - m1*w.x;  c11 += a1*u.y - m1*w.y;
    }
    B2s[i0][j0]=c00; B2s[i0][j0+1]=c01; B2s[i0+1][j0]=c10; B2s[i0+1][j0+1]=c11;
  }
  __syncthreads();
  const float bc = bta*(1.0f/12.0f);
  #pragma unroll
  for(int di=0;di<2;di++){
    #pragma unroll
    for(int dj=0;dj<2;dj++){
      int i=i0+di, jx=j0+dj;
      B0s[i][jx] = alpha*0.5f*(B0s[i][jx]+B1s[i][jx]) + bc*B2s[i][jx];  // omega
    }
  }
  __syncthreads();
  if(tid<64){
    float s=0.f;
    for(int i=0;i<64;i++) s += fabsf(B0s[i][tid]);
    colsum[tid]=s;
  }
  __syncthreads();
  if(tid==0){
    float m=0.f;
    for(int jx=0;jx<64;jx++) m = fmaxf(m, colsum[jx]);
    int s=0;
    while(m>0.5f && s<30){ m*=0.5f; s++; }
    ssh = s;
  }
  __syncthreads();
  int sh = ssh;
  float scl = ldexpf(1.0f, -sh);
  #pragma unroll
  for(int di=0;di<2;di++){
    #pragma unroll
    for(int dj=0;dj<2;dj++){ int i=i0+di,jx=j0+dj; B0s[i][jx]*=scl; }
  }
  __syncthreads();
  // Horner: P = I + A/8
  #pragma unroll
  for(int di=0;di<2;di++){
    #pragma unroll
    for(int dj=0;dj<2;dj++){
      int i=i0+di, jx=j0+dj;
      B1s[i][jx] = ((i==jx)?1.0f:0.0f) + B0s[i][jx]*0.125f;
    }
  }
  __syncthreads();
  for(int kk=7;kk>=1;kk--){
    float c00=0.f,c01=0.f,c10=0.f,c11=0.f;
    #pragma unroll 4
    for(int k=0;k<64;k++){
      float a0=B0s[i0][k], a1=B0s[i0+1][k];
      float2 u = *(const float2*)&B1s[k][j0];
      c00+=a0*u.x; c01+=a0*u.y; c10+=a1*u.x; c11+=a1*u.y;
    }
    B2s[i0][j0]=c00; B2s[i0][j0+1]=c01; B2s[i0+1][j0]=c10; B2s[i0+1][j0+1]=c11;
    __syncthreads();
    float inv = 1.0f/(float)kk;
    #pragma unroll
    for(int di=0;di<2;di++){
      #pragma unroll
      for(int dj=0;dj<2;dj++){
        int i=i0+di, jx=j0+dj;
        B1s[i][jx] = ((i==jx)?1.0f:0.0f) + B2s[i][jx]*inv;
      }
    }
    __syncthreads();
  }
  float (*Q)[66] = B1s; float (*T)[66] = B2s;
  for(int t=0;t<sh;t++){
    float c00=0.f,c01=0.f,c10=0.f,c11=0.f;
    #pragma unroll 4
    for(int k=0;k<64;k++){
      float a0=Q[i0][k], a1=Q[i0+1][k];
      float2 u = *(const float2*)&Q[k][j0];
      c00+=a0*u.x; c01+=a0*u.y; c10+=a1*u.x; c11+=a1*u.y;
    }
    T[i0][j0]=c00; T[i0][j0+1]=c01; T[i0+1][j0]=c10; T[i0+1][j0+1]=c11;
    __syncthreads();
    float (*tmp)[66]=Q; Q=T; T=tmp;
  }
  float g0 = gains[b*64+j0], g1 = gains[b*64+j0+1];
  float* mf = Mfin + b*4096;
  #pragma unroll
  for(int di=0;di<2;di++){
    int i=i0+di;
    float2 v;
    v.x = gate*(Q[i][j0]*g0   - ((i==j0)?1.0f:0.0f));
    v.y = gate*(Q[i][j0+1]*g1 - ((i==j0+1)?1.0f:0.0f));
    *(float2*)&mf[i*64+j0] = v;
  }
}

// ---------------- K8: C_b = Mfin_b @ output_basis ----------------
__global__ __launch_bounds__(256) void k8_cmat(const float* __restrict__ Mfin, const float* __restrict__ ob, float* __restrict__ C){
  __shared__ __align__(16) float MT[64][68];
  int b = blockIdx.y; int o0 = blockIdx.x*128;
  int tid = threadIdx.x;
  for(int idx=tid; idx<4096; idx+=256){ int i=idx>>6, k=idx&63; MT[k][i] = Mfin[b*4096+idx]; }
  __syncthreads();
  int cg = tid&31, rg = tid>>5;
  float acc[8][4];
  #pragma unroll
  for(int r=0;r<8;r++){ acc[r][0]=0.f; acc[r][1]=0.f; acc[r][2]=0.f; acc[r][3]=0.f; }
  for(int k=0;k<64;k++){
    float4 bv = *(const float4*)&ob[(size_t)k*NO + o0 + cg*4];
    float4 a0 = *(const float4*)&MT[k][rg*8];
    float4 a1 = *(const float4*)&MT[k][rg*8+4];
    float arr[8]={a0.x,a0.y,a0.z,a0.w,a1.x,a1.y,a1.z,a1.w};
    #pragma unroll
    for(int r=0;r<8;r++){
      acc[r][0]+=arr[r]*bv.x; acc[r][1]+=arr[r]*bv.y; acc[r][2]+=arr[r]*bv.z; acc[r][3]+=arr[r]*bv.w;
    }
  }
  #pragma unroll
  for(int r=0;r<8;r++){
    *(float4*)&C[((size_t)(b*64 + rg*8+r))*NO + o0 + cg*4] = make_float4(acc[r][0],acc[r][1],acc[r][2],acc[r][3]);
  }
}

// ---------------- K9: out_b = proj_b @ C_b ----------------
__global__ __launch_bounds__(256) void k9_out(const float* __restrict__ proj, const float* __restrict__ C, float* __restrict__ out){
  __shared__ __align__(16) float PT[64][132];
  __shared__ __align__(16) float CS[64][68];
  int b = blockIdx.z; int row0 = blockIdx.y*128; int o0 = blockIdx.x*64;
  int tid = threadIdx.x;
  #pragma unroll
  for(int i=0;i<8;i++){
    int f = tid + 256*i; int r = f>>4; int kv = f&15;
    float4 v = *(const float4*)&proj[((size_t)(b*NN + row0 + r))*NR + kv*4];
    PT[kv*4+0][r]=v.x; PT[kv*4+1][r]=v.y; PT[kv*4+2][r]=v.z; PT[kv*4+3][r]=v.w;
  }
  #pragma unroll
  for(int i=0;i<4;i++){
    int f = tid + 256*i; int k = f>>4; int kv = f&15;
    *(float4*)&CS[k][kv*4] = *(const float4*)&C[((size_t)(b*NR + k))*NO + o0 + kv*4];
  }
  __syncthreads();
  int rg = tid>>4, cg = tid&15;
  float acc[8][4];
  #pragma unroll
  for(int r=0;r<8;r++){ acc[r][0]=0.f; acc[r][1]=0.f; acc[r][2]=0.f; acc[r][3]=0.f; }
  #pragma unroll 8
  for(int k=0;k<64;k++){
    float4 bv = *(const float4*)&CS[k][cg*4];
    float4 a0 = *(const float4*)&PT[k][rg*8];
    float4 a1 = *(const float4*)&PT[k][rg*8+4];
    float arr[8]={a0.x,a0.y,a0.z,a0.w,a1.x,a1.y,a1.z,a1.w};
    #pragma unroll
    for(int r=0;r<8;r++){
      acc[r][0]+=arr[r]*bv.x; acc[r][1]+=arr[r]*bv.y; acc[r][2]+=arr[r]*bv.z; acc[r][3]+=arr[r]*bv.w;
    }
  }
  #pragma unroll
  for(int r=0;r<8;r++){
    *(float4*)&out[((size_t)(b*NN + row0 + rg*8 + r))*NO + o0 + cg*4] =
        make_float4(acc[r][0],acc[r][1],acc[r][2],acc[r][3]);
  }
}

extern "C" void kernel_launch(void* const* d_in, const int* in_sizes, int n_in,
                              void* d_out, int out_size, void* d_ws, size_t ws_size,
                              hipStream_t stream) {
  (void)in_sizes; (void)n_in; (void)out_size; (void)ws_size;
  const float* x       = (const float*)d_in[0];
  const float* context = (const float*)d_in[1];
  const float* ibasis  = (const float*)d_in[2];
  const float* obasis  = (const float*)d_in[3];
  const float* lng     = (const float*)d_in[4];
  const float* lnb     = (const float*)d_in[5];
  const float* w1      = (const float*)d_in[6];
  const float* b1      = (const float*)d_in[7];
  const float* w2      = (const float*)d_in[8];
  const float* b2      = (const float*)d_in[9];
  const float* wg      = (const float*)d_in[10];
  const float* bg      = (const float*)d_in[11];
  const float* wl      = (const float*)d_in[12];
  const float* bl      = (const float*)d_in[13];
  const float* wm      = (const float*)d_in[14];
  const float* bm      = (const float*)d_in[15];
  const float* wgain   = (const float*)d_in[16];
  const float* bgain   = (const float*)d_in[17];
  const float* wgate   = (const float*)d_in[18];
  const float* bgate   = (const float*)d_in[19];
  const float* wa      = (const float*)d_in[20];
  const float* ba      = (const float*)d_in[21];
  const float* wb      = (const float*)d_in[22];
  const float* bb      = (const float*)d_in[23];
  float* out = (float*)d_out;
  float* ws  = (float*)d_ws;

  float* pm    = ws + OFF_PM;
  float* pmsq  = ws + OFF_PMSQ;
  float* rowsq = ws + OFF_ROWSQ;
  float* G     = ws + OFF_G;
  float* h0    = ws + OFF_H0;
  float* h1    = ws + OFF_H1;
  float* lcl   = ws + OFF_LOCAL;
  float* p1    = ws + OFF_P1;
  float* p2    = ws + OFF_P2;
  float* pg_   = ws + OFF_PG;
  float* part  = ws + OFF_PG;   // alias: consumed by k1 before pg_ is written
  float* pl_   = ws + OFF_PL;
  float* Ag    = ws + OFF_AG;
  float* Al    = ws + OFF_AL;
  float* mask  = ws + OFF_MASK;
  float* gains = ws + OFF_GAINS;
  float* scal  = ws + OFF_SCAL;
  float* Mfin  = ws + OFF_MFIN;
  float* Cb    = ws + OFF_C;
  float* proj  = ws + OFF_PROJ;

  k0_colsum<<<dim3(16,NB),256,0,stream>>>(x, part);
  k1_pmreduce<<<NB,256,0,stream>>>(part, pm, pmsq);
  k2_proj<<<512,256,0,stream>>>(x, ibasis, pm, proj, rowsq, G);
  k3_detail<<<NB,256,0,stream>>>(x, rowsq, G, pmsq, lng, lnb, h0);
  gemm32_partial<<<dim3(2,8),256,0,stream>>>(h0, w1, p1, 1024, 512);
  k_red_gelu<<<64,256,0,stream>>>(p1, b1, h1);
  gemm32_partial<<<dim3(2,4),256,0,stream>>>(h1, w2, p2, 512, 512);
  k_red_local<<<64,256,0,stream>>>(p2, b2, lcl);
  gemm32_partial<<<dim3(16,4),256,0,stream>>>(context, wg, pg_, 512, 4096);
  gemm32_partial<<<dim3(16,4),256,0,stream>>>(lcl, wl, pl_, 512, 4096);
  k_red_gl<<<512,256,0,stream>>>(pg_, pl_, bg, bl, Ag, Al);
  k_heads<<<NB,1024,0,stream>>>(context, lcl, wm, bm, wgain, bgain, wgate, bgate, wa, ba, wb, bb, mask, gains, scal);
  k7_expm<<<NB,1024,0,stream>>>(Ag, Al, mask, gains, scal, Mfin);
  k8_cmat<<<dim3(8,NB),256,0,stream>>>(Mfin, obasis, Cb);
  k9_out<<<dim3(16,8,NB),256,0,stream>>>(proj, Cb, out);
}